// Round 1
// baseline (512.045 us; speedup 1.0000x reference)
//
#include <hip/hip_runtime.h>
#include <hip/hip_bf16.h>
#include <cstdint>
#include <cstddef>

#define HW    16384
#define TOPT  1638
#define NBINS 2048
#define BLK   256

// order-preserving float<->key transform (descending value = descending key)
__device__ __forceinline__ unsigned f2k(float f) {
  unsigned u = __float_as_uint(f);
  return (u & 0x80000000u) ? ~u : (u | 0x80000000u);
}
__device__ __forceinline__ float k2f(unsigned k) {
  unsigned u = (k & 0x80000000u) ? (k ^ 0x80000000u) : ~k;
  return __uint_as_float(u);
}
// linear bins over [-5,5]; monotone in v; clamped
__device__ __forceinline__ int binOf(float v) {
  int b = (int)((v + 5.0f) * 204.8f);   // 2048/10
  b = b < 0 ? 0 : b;
  return b > (NBINS - 1) ? (NBINS - 1) : b;
}

__global__ __launch_bounds__(BLK) void pools_kernel(const float* __restrict__ x,
                                                    float* __restrict__ avgp,
                                                    float* __restrict__ maxp) {
  __shared__ unsigned short keys[HW];     // 32 KB: bf16-precision sortable keys
  __shared__ unsigned hist[NBINS];        // 8 KB
  __shared__ unsigned scan[BLK];
  __shared__ float fred[3][4];
  __shared__ float wmax[4];
  __shared__ int s_bin, s_above;

  const int tid  = threadIdx.x;
  const int wid  = tid >> 6;
  const int lane = tid & 63;
  const int bc   = blockIdx.x;
  const float4* __restrict__ x4 = (const float4*)(x + (size_t)bc * HW);

  // zero histogram
  #pragma unroll
  for (int j = 0; j < NBINS / BLK; ++j) hist[j * BLK + tid] = 0u;

  // ---- load pass: keys -> LDS, exact max in registers ----
  float vmax = -3.4e38f;
  #pragma unroll
  for (int j = 0; j < HW / 4 / BLK; ++j) {   // 16 iters
    int i4 = j * BLK + tid;
    float4 v = x4[i4];
    ushort4 p;
    p.x = (unsigned short)(f2k(v.x) >> 16);
    p.y = (unsigned short)(f2k(v.y) >> 16);
    p.z = (unsigned short)(f2k(v.z) >> 16);
    p.w = (unsigned short)(f2k(v.w) >> 16);
    *reinterpret_cast<ushort4*>(&keys[(size_t)i4 * 4]) = p;
    vmax = fmaxf(vmax, fmaxf(fmaxf(v.x, v.y), fmaxf(v.z, v.w)));
  }
  #pragma unroll
  for (int off = 32; off; off >>= 1) vmax = fmaxf(vmax, __shfl_down(vmax, off, 64));
  if (lane == 0) wmax[wid] = vmax;
  __syncthreads();

  // ---- histogram pass (linear bins -> near-zero atomic contention) ----
  const unsigned* k32 = reinterpret_cast<const unsigned*>(keys);
  #pragma unroll 4
  for (int j = 0; j < HW / 2 / BLK; ++j) {   // 32 iters, 2 keys per read
    unsigned pk = k32[j * BLK + tid];
    float v0 = k2f(((pk & 0xFFFFu) << 16) | 0x8000u);
    float v1 = k2f((pk & 0xFFFF0000u) | 0x8000u);
    atomicAdd(&hist[binOf(v0)], 1u);
    atomicAdd(&hist[binOf(v1)], 1u);
  }
  __syncthreads();

  // ---- suffix-scan (from high bins) to locate threshold bin ----
  unsigned csum = 0;
  #pragma unroll
  for (int j = 0; j < NBINS / BLK; ++j) csum += hist[tid * (NBINS / BLK) + j];
  scan[tid] = csum;
  __syncthreads();
  for (int off = 1; off < BLK; off <<= 1) {
    unsigned v = (tid + off < BLK) ? scan[tid + off] : 0u;
    __syncthreads();
    scan[tid] += v;
    __syncthreads();
  }
  {
    unsigned S = scan[tid];        // elements in chunks >= tid
    unsigned A = S - csum;         // elements in chunks strictly above
    if (A < (unsigned)TOPT && (unsigned)TOPT <= S) {
      unsigned cum = A;
      for (int j = NBINS / BLK - 1; j >= 0; --j) {
        unsigned c = hist[tid * (NBINS / BLK) + j];
        if (cum + c >= (unsigned)TOPT) { s_bin = tid * (NBINS / BLK) + j; s_above = (int)cum; break; }
        cum += c;
      }
    }
  }
  __syncthreads();

  // ---- final pass: sum above threshold bin + eq-bin stats ----
  float sum_gt = 0.f, sum_eq = 0.f, cnt_eq = 0.f;
  const int bsel = s_bin;
  #pragma unroll 4
  for (int j = 0; j < HW / 2 / BLK; ++j) {
    unsigned pk = k32[j * BLK + tid];
    float v0 = k2f(((pk & 0xFFFFu) << 16) | 0x8000u);
    float v1 = k2f((pk & 0xFFFF0000u) | 0x8000u);
    int b0 = binOf(v0), b1 = binOf(v1);
    if (b0 > bsel) sum_gt += v0; else if (b0 == bsel) { sum_eq += v0; cnt_eq += 1.f; }
    if (b1 > bsel) sum_gt += v1; else if (b1 == bsel) { sum_eq += v1; cnt_eq += 1.f; }
  }
  #pragma unroll
  for (int off = 32; off; off >>= 1) {
    sum_gt += __shfl_down(sum_gt, off, 64);
    sum_eq += __shfl_down(sum_eq, off, 64);
    cnt_eq += __shfl_down(cnt_eq, off, 64);
  }
  if (lane == 0) { fred[0][wid] = sum_gt; fred[1][wid] = sum_eq; fred[2][wid] = cnt_eq; }
  __syncthreads();
  if (tid == 0) {
    float sg = fred[0][0] + fred[0][1] + fred[0][2] + fred[0][3];
    float se = fred[1][0] + fred[1][1] + fred[1][2] + fred[1][3];
    float ce = fred[2][0] + fred[2][1] + fred[2][2] + fred[2][3];
    float mx = fmaxf(fmaxf(wmax[0], wmax[1]), fmaxf(wmax[2], wmax[3]));
    float krem = (float)(TOPT - s_above);
    avgp[bc] = (sg + krem * (se / ce)) * (1.0f / (float)TOPT);
    maxp[bc] = mx;
  }
}

__global__ __launch_bounds__(128) void mlp_kernel(const float* __restrict__ avgp,
                                                  const float* __restrict__ maxp,
                                                  const float* __restrict__ w1,
                                                  const float* __restrict__ b1,
                                                  const float* __restrict__ w2,
                                                  const float* __restrict__ b2,
                                                  float* __restrict__ scale) {
  __shared__ float pa[128], pm[128], ha[8], hm[8];
  const int b = blockIdx.x, c = threadIdx.x;
  pa[c] = avgp[b * 128 + c];
  pm[c] = maxp[b * 128 + c];
  __syncthreads();
  if (c < 16) {
    const int h = c & 7;
    const bool isa = c < 8;
    const float* p = isa ? pa : pm;
    float acc = b1[h];
    for (int j = 0; j < 128; ++j) acc += p[j] * w1[j * 8 + h];
    float r = fmaxf(acc, 0.f);
    if (isa) ha[h] = r; else hm[h] = r;
  }
  __syncthreads();
  float att = 2.f * b2[c];
  #pragma unroll
  for (int h = 0; h < 8; ++h) att += (ha[h] + hm[h]) * w2[h * 128 + c];
  scale[b * 128 + c] = 1.f / (1.f + expf(-att));
}

__global__ __launch_bounds__(BLK) void scale_kernel(const float* __restrict__ x,
                                                    const float* __restrict__ scale,
                                                    float* __restrict__ out) {
  const int bc = blockIdx.x;
  const float s = scale[bc];
  const float4* __restrict__ x4 = (const float4*)(x + (size_t)bc * HW);
  float4* __restrict__ o4 = (float4*)(out + (size_t)bc * HW);
  #pragma unroll
  for (int j = 0; j < HW / 4 / BLK; ++j) {   // 16 iters
    int i = j * BLK + threadIdx.x;
    float4 v = x4[i];
    v.x *= s; v.y *= s; v.z *= s; v.w *= s;
    o4[i] = v;
  }
}

extern "C" void kernel_launch(void* const* d_in, const int* in_sizes, int n_in,
                              void* d_out, int out_size, void* d_ws, size_t ws_size,
                              hipStream_t stream) {
  const float* x  = (const float*)d_in[0];
  const float* w1 = (const float*)d_in[1];
  const float* b1 = (const float*)d_in[2];
  const float* w2 = (const float*)d_in[3];
  const float* b2 = (const float*)d_in[4];
  float* out = (float*)d_out;

  float* avgp  = (float*)d_ws;      // 4096 floats
  float* maxp  = avgp + 4096;       // 4096 floats
  float* scale = maxp + 4096;       // 4096 floats

  pools_kernel<<<4096, BLK, 0, stream>>>(x, avgp, maxp);
  mlp_kernel<<<32, 128, 0, stream>>>(avgp, maxp, w1, b1, w2, b2, scale);
  scale_kernel<<<4096, BLK, 0, stream>>>(x, scale, out);
}